// Round 1
// baseline (436.501 us; speedup 1.0000x reference)
//
#include <hip/hip_runtime.h>
#include <math.h>

#define B   32
#define N   512
#define M   512
#define DIM 64

#define INF __builtin_huge_valf()

// ---------------------------------------------------------------------------
// Kernel 1: D[b][i][j] = ||x_i||^2 + ||y_j||^2 - 2 * <x_i, y_j>
// 64x64 output tile per block, 256 threads, 4x4 micro-tile per thread.
// DIM=64 fits in one LDS tile -> load once, 64 d-iterations, write out.
// LDS stored transposed [d][i] (row stride 68 floats = 16B multiple, breaks
// power-of-2 bank stride) so compute reads are contiguous float4s.
// ---------------------------------------------------------------------------
__global__ __launch_bounds__(256) void pairdist_kernel(const float* __restrict__ X,
                                                       const float* __restrict__ Y,
                                                       float* __restrict__ Dout) {
    const int b  = blockIdx.z;
    const int i0 = blockIdx.y * 64;
    const int j0 = blockIdx.x * 64;

    __shared__ float Xt[DIM][68];
    __shared__ float Yt[DIM][68];

    const int tid = threadIdx.x;
    // Stage: 64 rows x 64 dims each for X and Y. Coalesced float4 global reads.
    {
        const int lr = tid >> 4;          // 0..15 (row group)
        const int lc = (tid & 15) << 2;   // 0..60 (d offset, float4)
        const float* xp = X + ((size_t)b * N + i0) * DIM;
        const float* yp = Y + ((size_t)b * M + j0) * DIM;
        #pragma unroll
        for (int rr = 0; rr < 64; rr += 16) {
            const int r = lr + rr;
            float4 xv = *(const float4*)(xp + (size_t)r * DIM + lc);
            Xt[lc + 0][r] = xv.x;
            Xt[lc + 1][r] = xv.y;
            Xt[lc + 2][r] = xv.z;
            Xt[lc + 3][r] = xv.w;
            float4 yv = *(const float4*)(yp + (size_t)r * DIM + lc);
            Yt[lc + 0][r] = yv.x;
            Yt[lc + 1][r] = yv.y;
            Yt[lc + 2][r] = yv.z;
            Yt[lc + 3][r] = yv.w;
        }
    }
    __syncthreads();

    const int tx = (tid & 15) << 2;  // j offset within tile (0..60)
    const int ty = (tid >> 4) << 2;  // i offset within tile (0..60)

    float acc[4][4] = {};
    float xs2[4] = {};
    float ys2[4] = {};

    #pragma unroll 4
    for (int d = 0; d < DIM; ++d) {
        float4 xv = *(const float4*)&Xt[d][ty];
        float4 yv = *(const float4*)&Yt[d][tx];
        float xa[4] = {xv.x, xv.y, xv.z, xv.w};
        float ya[4] = {yv.x, yv.y, yv.z, yv.w};
        #pragma unroll
        for (int a = 0; a < 4; ++a) {
            xs2[a] = fmaf(xa[a], xa[a], xs2[a]);
            ys2[a] = fmaf(ya[a], ya[a], ys2[a]);
            #pragma unroll
            for (int c = 0; c < 4; ++c)
                acc[a][c] = fmaf(xa[a], ya[c], acc[a][c]);
        }
    }

    float* dp = Dout + (((size_t)b * N + (i0 + ty)) * M + j0 + tx);
    #pragma unroll
    for (int a = 0; a < 4; ++a) {
        float4 o;
        o.x = xs2[a] + ys2[0] - 2.0f * acc[a][0];
        o.y = xs2[a] + ys2[1] - 2.0f * acc[a][1];
        o.z = xs2[a] + ys2[2] - 2.0f * acc[a][2];
        o.w = xs2[a] + ys2[3] - 2.0f * acc[a][3];
        *(float4*)(dp + (size_t)a * M) = o;
    }
}

// ---------------------------------------------------------------------------
// Kernel 2: soft-DTW DP over anti-diagonals.
// One block per batch, 512 threads; thread tid owns row i = tid+1.
// Three rolling diagonal buffers in LDS indexed by row i:
//   at step t: p2[i] = R[i, t-2-i], p1[i] = R[i, t-1-i], cur[i] = R[i, t-i]
//   R[i-1,j-1] = p2[i-1], R[i-1,j] = p1[i-1], R[i,j-1] = p1[i]
// One __syncthreads per diagonal. D row read is sequential per thread ->
// register prefetch one iteration ahead (address is DP-independent).
// ---------------------------------------------------------------------------
__global__ __launch_bounds__(512) void dtw_kernel(const float* __restrict__ Dmat,
                                                  float* __restrict__ out) {
    const int b = blockIdx.x;
    const float* Db = Dmat + (size_t)b * N * M;

    __shared__ float buf[3][N + 1];   // 3 * 513 * 4 B = ~6.2 KB

    const int tid = threadIdx.x;
    float* bufflat = &buf[0][0];
    for (int k = tid; k < 3 * (N + 1); k += 512) bufflat[k] = INF;
    __syncthreads();
    if (tid == 0) buf[0][0] = 0.0f;   // R[0,0] = 0 (diagonal t=0)
    __syncthreads();

    const int i = tid + 1;                       // row 1..512
    const float* drow = Db + (size_t)(i - 1) * M;
    float dval = drow[0];                        // D[i-1][0], used when j==1

    int p2 = 0, p1 = 1, cur = 2;
    float val = INF;

    for (int t = 2; t <= N + M; ++t) {
        const int j = t - i;
        const float ra = buf[p2][i - 1];   // R[i-1, j-1]
        const float rb = buf[p1][i - 1];   // R[i-1, j]
        const float rc = buf[p1][i];       // R[i,   j-1]

        // softmin, gamma = 1 (NaN possible on invalid lanes; discarded below)
        const float r0 = -ra, r1 = -rb, r2 = -rc;
        const float rmax = fmaxf(fmaxf(r0, r1), r2);
        const float rsum = __expf(r0 - rmax) + __expf(r1 - rmax) + __expf(r2 - rmax);
        const float softmin = -(__logf(rsum) + rmax);

        const bool valid = (j >= 1) && (j <= M);
        val = valid ? (dval + softmin) : INF;
        buf[cur][i] = val;
        if (tid == 0) buf[cur][0] = INF;   // R[0, t] = inf

        // prefetch D[i-1][j] for next iteration (its j-1 == this j)
        if (j >= 1 && j < M) dval = drow[j];

        __syncthreads();
        const int tmp = p2; p2 = p1; p1 = cur; cur = tmp;
    }

    if (i == N) out[b] = val;   // R[N, M] lives on diagonal t = N+M at row N
}

extern "C" void kernel_launch(void* const* d_in, const int* in_sizes, int n_in,
                              void* d_out, int out_size, void* d_ws, size_t ws_size,
                              hipStream_t stream) {
    const float* X = (const float*)d_in[0];
    const float* Y = (const float*)d_in[1];
    float* outp = (float*)d_out;
    float* Dmat = (float*)d_ws;   // B*N*M*4 = 32 MB scratch

    dim3 g1(M / 64, N / 64, B);
    pairdist_kernel<<<g1, dim3(256), 0, stream>>>(X, Y, Dmat);
    dtw_kernel<<<dim3(B), dim3(512), 0, stream>>>(Dmat, outp);
}

// Round 2
// 413.757 us; speedup vs baseline: 1.0550x; 1.0550x over previous
//
#include <hip/hip_runtime.h>
#include <math.h>

#define B   32
#define N   512
#define M   512
#define DIM 64

#define INF __builtin_huge_valf()
#define LOG2E 1.44269504088896340736f
#define LN2   0.69314718055994530942f

#if __has_builtin(__builtin_amdgcn_exp2f)
#define fast_exp2 __builtin_amdgcn_exp2f
#else
#define fast_exp2 exp2f
#endif
#if __has_builtin(__builtin_amdgcn_logf)
#define fast_log2 __builtin_amdgcn_logf   /* v_log_f32 computes log2 */
#else
#define fast_log2 log2f
#endif

__device__ __forceinline__ float readlane_f(float v, int srcLane) {
    return __uint_as_float(__builtin_amdgcn_readlane(__float_as_uint(v), srcLane));
}

// softmin in base-2 scaled domain: result = d + lo - log2(1 + 2^(lo-mid) + 2^(lo-hi))
// One of {a,b,c} equals lo, so its exp2 term is exactly 1 -> only 2 exp2 + 1 log2.
// INF-safe for valid cells (>=1 finite input); all-INF only on masked lanes.
__device__ __forceinline__ float softmin_cell(float a, float b, float c, float d, bool valid) {
    float lo  = fminf(fminf(a, b), c);
    float hi  = fmaxf(fmaxf(a, b), c);
    float mid = __builtin_amdgcn_fmed3f(a, b, c);
    float e1 = fast_exp2(lo - mid);
    float e2 = fast_exp2(lo - hi);
    float s  = 1.0f + e1 + e2;
    float r  = d + (lo - fast_log2(s));
    return valid ? r : INF;
}

// ---------------------------------------------------------------------------
// Kernel 1: D'[b][i][j] = (||x_i||^2 + ||y_j||^2 - 2<x_i,y_j>) * log2(e)
// (scaled domain for the DP kernel). 64x64 tile / block, 256 thr, 4x4 micro.
// ---------------------------------------------------------------------------
__global__ __launch_bounds__(256) void pairdist_kernel(const float* __restrict__ X,
                                                       const float* __restrict__ Y,
                                                       float* __restrict__ Dout) {
    const int b  = blockIdx.z;
    const int i0 = blockIdx.y * 64;
    const int j0 = blockIdx.x * 64;

    __shared__ float Xt[DIM][68];
    __shared__ float Yt[DIM][68];

    const int tid = threadIdx.x;
    {
        const int lr = tid >> 4;
        const int lc = (tid & 15) << 2;
        const float* xp = X + ((size_t)b * N + i0) * DIM;
        const float* yp = Y + ((size_t)b * M + j0) * DIM;
        #pragma unroll
        for (int rr = 0; rr < 64; rr += 16) {
            const int r = lr + rr;
            float4 xv = *(const float4*)(xp + (size_t)r * DIM + lc);
            Xt[lc + 0][r] = xv.x;
            Xt[lc + 1][r] = xv.y;
            Xt[lc + 2][r] = xv.z;
            Xt[lc + 3][r] = xv.w;
            float4 yv = *(const float4*)(yp + (size_t)r * DIM + lc);
            Yt[lc + 0][r] = yv.x;
            Yt[lc + 1][r] = yv.y;
            Yt[lc + 2][r] = yv.z;
            Yt[lc + 3][r] = yv.w;
        }
    }
    __syncthreads();

    const int tx = (tid & 15) << 2;
    const int ty = (tid >> 4) << 2;

    float acc[4][4] = {};
    float xs2[4] = {};
    float ys2[4] = {};

    #pragma unroll 4
    for (int d = 0; d < DIM; ++d) {
        float4 xv = *(const float4*)&Xt[d][ty];
        float4 yv = *(const float4*)&Yt[d][tx];
        float xa[4] = {xv.x, xv.y, xv.z, xv.w};
        float ya[4] = {yv.x, yv.y, yv.z, yv.w};
        #pragma unroll
        for (int a = 0; a < 4; ++a) {
            xs2[a] = fmaf(xa[a], xa[a], xs2[a]);
            ys2[a] = fmaf(ya[a], ya[a], ys2[a]);
            #pragma unroll
            for (int c = 0; c < 4; ++c)
                acc[a][c] = fmaf(xa[a], ya[c], acc[a][c]);
        }
    }

    float* dp = Dout + (((size_t)b * N + (i0 + ty)) * M + j0 + tx);
    #pragma unroll
    for (int a = 0; a < 4; ++a) {
        float4 o;
        o.x = (xs2[a] + ys2[0] - 2.0f * acc[a][0]) * LOG2E;
        o.y = (xs2[a] + ys2[1] - 2.0f * acc[a][1]) * LOG2E;
        o.z = (xs2[a] + ys2[2] - 2.0f * acc[a][2]) * LOG2E;
        o.w = (xs2[a] + ys2[3] - 2.0f * acc[a][3]) * LOG2E;
        *(float4*)(dp + (size_t)a * M) = o;
    }
}

// ---------------------------------------------------------------------------
// Kernel 2: soft-DTW DP, skewed tile wavefront.
// 1 block/batch, 4 waves x 64 lanes, 2 contiguous rows/lane (wave w owns rows
// 128w+1..128w+128). Wave w processes diagonal-chunk c (33 diagonals) at
// superstep s=c+w; barrier once per superstep (34 total vs 1023 before).
// Rolling diagonal state (p2/p1/cur per row) in registers, 3-phase rotation.
// Intra-wave comms: shfl_up. Inter-wave boundary row: LDS ring, bulk-read
// once per chunk, per-step v_readlane. D prefetched 3 steps ahead.
// ---------------------------------------------------------------------------
#define S_CH  33
#define C_CH  31          /* 33*31 = 1023 diagonals, t = 2..1024 */
#define RING  128
#define RINGM 127

#define STEP(P2_0,P1_0,CU_0, P2_1,P1_1,CU_1, DQ0, DQ1) do {                 \
    float u2 = __shfl_up(P2_1, 1);                                          \
    float u1 = __shfl_up(P1_1, 1);                                          \
    float rbv = readlane_f(vchunk, kk + 1);                                 \
    if (lane == 0) { u2 = sra; u1 = rbv; }                                  \
    sra = rbv;                                                              \
    const bool v0 = (t > i0);                                               \
    const bool v1 = (t > i1);                                               \
    CU_0 = softmin_cell(u2,   u1,   P1_0, DQ0, v0);                         \
    CU_1 = softmin_cell(P2_0, P1_0, P1_1, DQ1, v1);                         \
    if (lane == 63) ringw[t & RINGM] = CU_1;                                \
    if (t == N + M) res = CU_1;                                             \
    DQ0 = Db[off0 + 3];                                                     \
    DQ1 = Db[off1 + 3];                                                     \
    ++off0; ++off1; ++t; ++kk;                                              \
} while (0)

__global__ __launch_bounds__(256) void dtw_kernel(const float* __restrict__ Dmat,
                                                  float* __restrict__ out) {
    const int b = blockIdx.x;
    const float* __restrict__ Db = Dmat + (size_t)b * N * M;

    __shared__ float ring[4][RING];

    const int tid  = threadIdx.x;
    const int w    = tid >> 6;
    const int lane = tid & 63;
    const int i0   = 128 * w + 2 * lane + 1;   // first owned row
    const int i1   = i0 + 1;                    // second owned row

    float* __restrict__ ringw = ring[w];
    const float* __restrict__ ringr = ring[(w + 3) & 3];  // wave w-1 (unused for w==0)

    // byte/element offsets into D for (row, t): off = (i-1)*M + (t - i - 1), at t=2
    int off0 = (i0 - 1) * M + 1 - i0;
    int off1 = i0 * M - i0;

    // rolling diagonal registers: A=p2, B=p1, C=cur (3-phase rotation)
    float A0 = INF, B0 = INF, C0 = INF;
    float A1 = INF, B1 = INF, C1 = INF;

    // D prefetch queues (depth 3, matches rotation period)
    float d0a = Db[off0], d0b = Db[off0 + 1], d0c = Db[off0 + 2];
    float d1a = Db[off1], d1b = Db[off1 + 1], d1c = Db[off1 + 2];

    int   t   = 2;
    float res = 0.0f;
    float sra = 0.0f;

    for (int s = 0; s < C_CH + 3; ++s) {
        if (s >= w && s < w + C_CH) {
            const int c = s - w;
            // Bulk-read this chunk's boundary-row values (entries 33c .. 33c+33).
            // For wave 0 the boundary is the R[0,*] row: 0 at diag 0, else INF.
            float vchunk;
            if (w == 0) {
                vchunk = (c == 0 && lane == 0) ? 0.0f : INF;
            } else {
                vchunk = ringr[(S_CH * c + lane) & RINGM];
            }
            int kk = 0;
            sra = readlane_f(vchunk, 0);
            for (int u = 0; u < S_CH / 3; ++u) {
                STEP(A0, B0, C0,  A1, B1, C1,  d0a, d1a);
                STEP(B0, C0, A0,  B1, C1, A1,  d0b, d1b);
                STEP(C0, A0, B0,  C1, A1, B1,  d0c, d1c);
            }
        }
        __syncthreads();
    }

    if (w == 3 && lane == 63) out[b] = res * LN2;
}

extern "C" void kernel_launch(void* const* d_in, const int* in_sizes, int n_in,
                              void* d_out, int out_size, void* d_ws, size_t ws_size,
                              hipStream_t stream) {
    const float* X = (const float*)d_in[0];
    const float* Y = (const float*)d_in[1];
    float* outp = (float*)d_out;
    float* Dmat = (float*)d_ws;   // B*N*M*4 = 32 MB scratch (scaled by log2e)

    dim3 g1(M / 64, N / 64, B);
    pairdist_kernel<<<g1, dim3(256), 0, stream>>>(X, Y, Dmat);
    dtw_kernel<<<dim3(B), dim3(256), 0, stream>>>(Dmat, outp);
}

// Round 3
// 248.026 us; speedup vs baseline: 1.7599x; 1.6682x over previous
//
#include <hip/hip_runtime.h>
#include <math.h>

#define B   32
#define N   512
#define M   512
#define DIM 64

#define INF __builtin_huge_valf()
#define LOG2E 1.44269504088896340736f
#define LN2   0.69314718055994530942f

#define NDIAG_ELEMS (N * M)         /* packed diag layout size per batch */

#if __has_builtin(__builtin_amdgcn_exp2f)
#define fast_exp2 __builtin_amdgcn_exp2f
#else
#define fast_exp2 exp2f
#endif
#if __has_builtin(__builtin_amdgcn_logf)
#define fast_log2 __builtin_amdgcn_logf   /* v_log_f32 computes log2 */
#else
#define fast_log2 log2f
#endif

__device__ __forceinline__ float readlane_f(float v, int srcLane) {
    return __uint_as_float(__builtin_amdgcn_readlane(__float_as_uint(v), srcLane));
}

// Packed anti-diagonal layout. Diag t = i + j (i,j 1-based), t in [2, 1024].
// L(t) = t<=513 ? t-1 : 1025-t ; off(t) = prefix sum (closed form below).
// Entry index within diag: (i - 1) - max(0, t - 513).
__device__ __forceinline__ int diag_off(int t) {
    return (t <= 513) ? (((t - 2) * (t - 1)) >> 1)
                      : (NDIAG_ELEMS - (((1025 - t) * (1026 - t)) >> 1));
}

// softmin in base-2 scaled domain: r = d + lo - log2(1 + 2^(lo-mid) + 2^(lo-hi))
// (lo term's exp2 is exactly 1 -> 2 exp2 + 1 log2). INF-safe for valid cells.
__device__ __forceinline__ float softmin_cell(float a, float b, float c, float d, bool valid) {
    float lo  = fminf(fminf(a, b), c);
    float hi  = fmaxf(fmaxf(a, b), c);
    float mid = __builtin_amdgcn_fmed3f(a, b, c);
    float e1 = fast_exp2(lo - mid);
    float e2 = fast_exp2(lo - hi);
    float s  = 1.0f + e1 + e2;
    float r  = d + (lo - fast_log2(s));
    return valid ? r : INF;
}

// ---------------------------------------------------------------------------
// Kernel 1: D'[t-diag packed] = (||x_i||^2 + ||y_j||^2 - 2<x_i,y_j>) * log2(e)
// 64x64 tile / block, 256 thr, 4x4 micro-tile. Epilogue stages tile in LDS
// (row stride 66 -> diagonal reads bank-conflict-free) and writes each of
// the 127 tile-diagonal segments as coalesced contiguous stores.
// ---------------------------------------------------------------------------
__global__ __launch_bounds__(256) void pairdist_kernel(const float* __restrict__ X,
                                                       const float* __restrict__ Y,
                                                       float* __restrict__ Dout) {
    const int b  = blockIdx.z;
    const int r0 = blockIdx.y * 64;   // 0-based row origin (i = r+1)
    const int c0 = blockIdx.x * 64;   // 0-based col origin (j = c+1)

    __shared__ float Xt[DIM][68];
    __shared__ float Yt[DIM][68];
    __shared__ float Ct[64][66];

    const int tid = threadIdx.x;
    {
        const int lr = tid >> 4;
        const int lc = (tid & 15) << 2;
        const float* xp = X + ((size_t)b * N + r0) * DIM;
        const float* yp = Y + ((size_t)b * M + c0) * DIM;
        #pragma unroll
        for (int rr = 0; rr < 64; rr += 16) {
            const int r = lr + rr;
            float4 xv = *(const float4*)(xp + (size_t)r * DIM + lc);
            Xt[lc + 0][r] = xv.x;
            Xt[lc + 1][r] = xv.y;
            Xt[lc + 2][r] = xv.z;
            Xt[lc + 3][r] = xv.w;
            float4 yv = *(const float4*)(yp + (size_t)r * DIM + lc);
            Yt[lc + 0][r] = yv.x;
            Yt[lc + 1][r] = yv.y;
            Yt[lc + 2][r] = yv.z;
            Yt[lc + 3][r] = yv.w;
        }
    }
    __syncthreads();

    const int tx = (tid & 15) << 2;
    const int ty = (tid >> 4) << 2;

    float acc[4][4] = {};
    float xs2[4] = {};
    float ys2[4] = {};

    #pragma unroll 4
    for (int d = 0; d < DIM; ++d) {
        float4 xv = *(const float4*)&Xt[d][ty];
        float4 yv = *(const float4*)&Yt[d][tx];
        float xa[4] = {xv.x, xv.y, xv.z, xv.w};
        float ya[4] = {yv.x, yv.y, yv.z, yv.w};
        #pragma unroll
        for (int a = 0; a < 4; ++a) {
            xs2[a] = fmaf(xa[a], xa[a], xs2[a]);
            ys2[a] = fmaf(ya[a], ya[a], ys2[a]);
            #pragma unroll
            for (int c = 0; c < 4; ++c)
                acc[a][c] = fmaf(xa[a], ya[c], acc[a][c]);
        }
    }

    #pragma unroll
    for (int a = 0; a < 4; ++a)
        #pragma unroll
        for (int c = 0; c < 4; ++c)
            Ct[ty + a][tx + c] = (xs2[a] + ys2[c] - 2.0f * acc[a][c]) * LOG2E;

    __syncthreads();

    // Diagonal writeout: td = a + b in [0,126]; entries contiguous in packed
    // layout as a increases. 4 diagonals in flight (one per 64-thread group).
    const int aa   = tid & 63;
    const int dgrp = tid >> 6;
    float* __restrict__ Dp = Dout + (size_t)b * NDIAG_ELEMS;
    #pragma unroll
    for (int g = 0; g < 32; ++g) {
        const int td = g * 4 + dgrp;          // 0..127 (127 unused)
        const int bb = td - aa;
        if (td < 127 && bb >= 0 && bb < 64) {
            const int t   = r0 + c0 + td + 2;
            const int sub = (t > 513) ? (t - 513) : 0;
            Dp[diag_off(t) + (r0 + aa) - sub] = Ct[aa][bb];
        }
    }
}

// ---------------------------------------------------------------------------
// Kernel 2: soft-DTW DP, skewed tile wavefront over the packed-diag D.
// 1 block/batch, 4 waves x 64 lanes, 2 consecutive rows/lane (wave w owns
// rows 128w+1..128w+128). Chunks of 32 diagonals; wave w runs chunk c at
// superstep s=c+w (35 supersteps, one barrier each). Per step the wave's
// 128 D values are 128 CONSECUTIVE floats -> 2 coalesced dword loads,
// register prefetch queue of depth 8 (slot = step & 7; 32 % 8 == 0 so the
// slot schedule repeats per chunk -> no dynamic indexing).
// Intra-wave comms: shfl_up. Inter-wave boundary row: 128-entry LDS ring.
// ---------------------------------------------------------------------------
#define S_CH  32
#define C_CH  32          /* 32*32 = 1024 steps, t = 2..1025 (1025 is pad) */
#define RINGM 127
#define PF    8

__global__ __launch_bounds__(256) void dtw_kernel(const float* __restrict__ Dmat,
                                                  float* __restrict__ out) {
    const int b = blockIdx.x;
    const float* __restrict__ Dp = Dmat + (size_t)b * NDIAG_ELEMS;

    __shared__ float ring[4][128];

    const int tid  = threadIdx.x;
    const int w    = tid >> 6;
    const int lane = tid & 63;
    const int i0   = 128 * w + 2 * lane + 1;   // first owned row (1-based)
    const int i1   = i0 + 1;
    const int r0l  = i0 - 1;                   // 0-based packed row index

    float* __restrict__ ringw = ring[w];
    const float* __restrict__ ringr = ring[(w + 3) & 3];

    // rolling diagonal state: p2 = R[row, t-2-row], p1 = R[row, t-1-row]
    float p2_0 = INF, p1_0 = INF;
    float p2_1 = INF, p1_1 = INF;

    // D prefetch queue, depth 8 (slot = (t-2) & 7)
    float qA[PF], qB[PF];
    int pf_t = 2, pf_off = 0;                  // wave-uniform
    #pragma unroll
    for (int p = 0; p < PF; ++p) {
        const int sub = (pf_t > 513) ? (pf_t - 513) : 0;
        int idx = pf_off + r0l - sub;
        idx = max(0, min(idx, NDIAG_ELEMS - 2));
        qA[p] = Dp[idx];
        qB[p] = Dp[idx + 1];
        pf_off += (pf_t <= 513) ? (pf_t - 1) : (1025 - pf_t);
        ++pf_t;
    }

    int   t   = 2;
    float res = 0.0f;

    for (int s = 0; s < C_CH + 3; ++s) {
        if (s >= w && s < w + C_CH) {
            const int c = s - w;
            // boundary row (producer wave w-1) for this chunk: steps 32c..32c+32
            float vchunk;
            if (w == 0) {
                vchunk = (c == 0 && lane == 0) ? 0.0f : INF;   // R[0, j]: 0 at j=0
            } else {
                vchunk = ringr[(S_CH * c + lane) & RINGM];
            }
            float sra = readlane_f(vchunk, 0);                 // entry t-2
            #pragma unroll
            for (int kk = 0; kk < S_CH; ++kk) {
                const int slot = kk & (PF - 1);
                float u2 = __shfl_up(p2_1, 1);
                float u1 = __shfl_up(p1_1, 1);
                const float rbv = readlane_f(vchunk, kk + 1);  // entry t-1
                if (lane == 0) { u2 = sra; u1 = rbv; }
                sra = rbv;
                const bool v0 = (t > i0);
                const bool v1 = (t > i1);
                const float c0v = softmin_cell(u2,   u1,   p1_0, qA[slot], v0);
                const float c1v = softmin_cell(p2_0, p1_0, p1_1, qB[slot], v1);
                if (lane == 63) ringw[t & RINGM] = c1v;
                if (t == N + M) res = c1v;
                p2_0 = p1_0; p1_0 = c0v;
                p2_1 = p1_1; p1_1 = c1v;
                // prefetch D for step t+8 into the slot just freed
                {
                    const int sub = (pf_t > 513) ? (pf_t - 513) : 0;
                    int idx = pf_off + r0l - sub;
                    idx = max(0, min(idx, NDIAG_ELEMS - 2));
                    qA[slot] = Dp[idx];
                    qB[slot] = Dp[idx + 1];
                    pf_off += (pf_t <= 513) ? (pf_t - 1) : (1025 - pf_t);
                    ++pf_t;
                }
                ++t;
            }
        }
        __syncthreads();
    }

    if (w == 3 && lane == 63) out[b] = res * LN2;
}

extern "C" void kernel_launch(void* const* d_in, const int* in_sizes, int n_in,
                              void* d_out, int out_size, void* d_ws, size_t ws_size,
                              hipStream_t stream) {
    const float* X = (const float*)d_in[0];
    const float* Y = (const float*)d_in[1];
    float* outp = (float*)d_out;
    float* Dmat = (float*)d_ws;   // B*N*M*4 = 32 MB, packed-diagonal layout

    dim3 g1(M / 64, N / 64, B);
    pairdist_kernel<<<g1, dim3(256), 0, stream>>>(X, Y, Dmat);
    dtw_kernel<<<dim3(B), dim3(256), 0, stream>>>(Dmat, outp);
}